// Round 3
// baseline (1509.208 us; speedup 1.0000x reference)
//
#include <hip/hip_runtime.h>
#include <hip/hip_bf16.h>
#include <hip/hip_fp16.h>

// Context encoder: BiGRU(256) -> LN1 -> MHA(8x64, masked) -> +res LN2
// Round 3: GRU scan rewritten — chunked LDS staging of xg (16 steps/chunk),
// LDS-buffered outputs flushed per chunk, single barrier per step, gates
// computed in-register from MFMA accumulators (no hg LDS round-trip).

typedef __bf16 bf16_t;
typedef _Float16 f16_t;
typedef __bf16 bf16x8 __attribute__((ext_vector_type(8)));
typedef __bf16 bf16x4 __attribute__((ext_vector_type(4)));
typedef _Float16 f16x8 __attribute__((ext_vector_type(8)));
typedef float f32x4 __attribute__((ext_vector_type(4)));

#define NB 32
#define NS 512
#define ND 512
#define NH 8
#define DKq 64
#define CH 16

static __device__ __forceinline__ float sigm(float x){ return 1.0f/(1.0f+__expf(-x)); }
static __device__ __forceinline__ float tanh_fast(float x){ return 1.0f - 2.0f/(__expf(2.0f*x)+1.0f); }

// ---------------- fp32 -> bf16 convert ----------------
__global__ void cvt_f32_bf16_k(const float* __restrict__ src, bf16_t* __restrict__ dst, int n4){
    int i = blockIdx.x*256 + threadIdx.x;
    if (i < n4){
        float4 v = ((const float4*)src)[i];
        bf16x4 o; o[0]=(bf16_t)v.x; o[1]=(bf16_t)v.y; o[2]=(bf16_t)v.z; o[3]=(bf16_t)v.w;
        ((bf16x4*)dst)[i] = o;
    }
}

// ---------------- generic bf16 MFMA GEMM: C = A(M,512) @ W(N,512)^T + bias ----------------
template<int MODE>
__global__ __launch_bounds__(256,2) void gemm_k(
    const bf16_t* __restrict__ A, const bf16_t* __restrict__ W,
    const float* __restrict__ bias, void* __restrict__ out,
    const int* __restrict__ masks, int N)
{
    const int lane = threadIdx.x & 63;
    const int wv = threadIdx.x >> 6;
    const int wr = wv >> 1, wc = wv & 1;
    const int m0 = blockIdx.y*128 + wr*64;
    const int n0 = blockIdx.x*128 + wc*64;
    const int r16 = lane & 15, kq = lane >> 4;
    f32x4 acc[4][4] = {};
    const bf16_t* Ap = A + (size_t)(m0 + r16)*512 + kq*8;
    const bf16_t* Wp = W + (size_t)(n0 + r16)*512 + kq*8;
    #pragma unroll
    for (int kk = 0; kk < 16; ++kk){
        bf16x8 a[4], b[4];
        #pragma unroll
        for (int i=0;i<4;++i) a[i] = *(const bf16x8*)(Ap + (size_t)i*16*512 + kk*32);
        #pragma unroll
        for (int j=0;j<4;++j) b[j] = *(const bf16x8*)(Wp + (size_t)j*16*512 + kk*32);
        #pragma unroll
        for (int i=0;i<4;++i)
            #pragma unroll
            for (int j=0;j<4;++j)
                acc[i][j] = __builtin_amdgcn_mfma_f32_16x16x32_bf16(a[i], b[j], acc[i][j], 0,0,0);
    }
    #pragma unroll
    for (int i=0;i<4;++i){
        int row_base = m0 + i*16 + kq*4;
        #pragma unroll
        for (int j=0;j<4;++j){
            int col = n0 + j*16 + r16;
            float bs = bias[col];
            #pragma unroll
            for (int r=0;r<4;++r){
                int row = row_base + r;
                float v = acc[i][j][r] + bs;
                if (MODE==0){
                    ((f16_t*)out)[(size_t)row*N + col] = (f16_t)v;
                } else if (MODE==1){
                    int which = col >> 9, hh = (col >> 6) & 7, d = col & 63;
                    int bb = row >> 9, s = row & 511;
                    ((bf16_t*)out)[((((size_t)which*NB + bb)*NH + hh)*NS + s)*DKq + d] = (bf16_t)v;
                } else {
                    float mrow = (float)masks[row];
                    ((float*)out)[(size_t)row*N + col] = v * mrow;
                }
            }
        }
    }
}

// ---------------- GRU scan: one block per (batch, dir), chunked staging ----------------
// Wave w owns h-elements [64w, 64w+64): tile tt -> n0 = (tt>>2)*256 + (4w+(tt&3))*16.
// After MFMA, lane r16 (kq==0), reg 0 of acc[gate*4+c] holds hg[gate*256 + 64w+16c+r16].
__global__ __launch_bounds__(256,1) void gru_scan_k(
    const f16_t* __restrict__ xg,          // (B*S, 1536): [fwd 768 | bwd 768]
    const float* __restrict__ whh_f, const float* __restrict__ whh_b,
    const float* __restrict__ bhh_f, const float* __restrict__ bhh_b,
    const int* __restrict__ lengths,
    f16_t* __restrict__ gout,              // (B*S, 512) pre-zeroed
    float* __restrict__ hidden)            // (B, 512)
{
    const int b = blockIdx.x >> 1, dir = blockIdx.x & 1;
    const int tid = threadIdx.x, lane = tid & 63, w = tid >> 6;
    const int r16 = lane & 15, kq = lane >> 4;
    const float* whh = dir ? whh_b : whh_f;
    const float* bhh = dir ? bhh_b : bhh_f;
    const int len = lengths[b];

    __shared__ __align__(16) bf16_t h_lds[16][264];     // M=16 A tile (row 0 real)
    __shared__ __align__(16) f16_t  xg_lds[CH][768];    // staged xg chunk
    __shared__ __align__(16) f16_t  go_lds[CH][256];    // output buffer

    for (int i = tid; i < 16*264; i += 256) (&h_lds[0][0])[i] = (bf16_t)0.0f;

    // w_hh B-fragments in registers; tile tt -> n0 = (tt>>2)*256 + (4w+(tt&3))*16
    bf16x8 wf[12][8];
    #pragma unroll
    for (int tt=0; tt<12; ++tt){
        int n0 = (tt>>2)*256 + (4*w + (tt&3))*16;
        const float* wp = whh + (size_t)(n0 + r16)*256 + kq*8;
        #pragma unroll
        for (int kk=0; kk<8; ++kk){
            float4 v0 = *(const float4*)(wp + kk*32);
            float4 v1 = *(const float4*)(wp + kk*32 + 4);
            bf16x8 f;
            f[0]=(bf16_t)v0.x; f[1]=(bf16_t)v0.y; f[2]=(bf16_t)v0.z; f[3]=(bf16_t)v0.w;
            f[4]=(bf16_t)v1.x; f[5]=(bf16_t)v1.y; f[6]=(bf16_t)v1.z; f[7]=(bf16_t)v1.w;
            wf[tt][kk] = f;
        }
    }
    // per-lane gate biases and h registers (lanes 0..15 of each wave)
    float bhr[4], bhz[4], bhn[4], hreg[4];
    #pragma unroll
    for (int c=0;c<4;++c){
        int g = 64*w + 16*c + r16;
        bhr[c] = bhh[g]; bhz[c] = bhh[256+g]; bhn[c] = bhh[512+g];
        hreg[c] = 0.0f;
    }

    const int t0 = dir ? (NS - len) : 0;
    const int t_end = dir ? NS : len;
    const int nch = (len + CH - 1) / CH;
    const int dirOff = dir * 768;
    __syncthreads();

    for (int ci = 0; ci < nch; ++ci){
        const int base = t0 + ci*CH;
        const int jmax = min(CH, t_end - base);
        // stage loads into regs (issued first to hide latency under the flush)
        f16x8 stg[6] = {};
        #pragma unroll
        for (int i=0;i<6;++i){
            int v = i*256 + tid;                 // 0..1535
            int row = v / 96, c8 = v - row*96;
            int t = base + row;
            if (t < t_end){
                int pos = dir ? (NS-1-t) : t;
                stg[i] = *(const f16x8*)(xg + ((size_t)b*NS + pos)*1536 + dirOff + c8*8);
            }
        }
        // flush previous chunk's outputs (prev chunk is always full)
        if (ci > 0){
            const int pbase = base - CH;
            #pragma unroll
            for (int q=0;q<2;++q){
                int v = q*256 + tid;             // 0..511
                int row = v >> 5, c8 = v & 31;
                int t = pbase + row;
                int pos = dir ? (NS-1-t) : t;
                f16x8 vv = *(const f16x8*)(&go_lds[row][c8*8]);
                *(f16x8*)(gout + ((size_t)b*NS + pos)*512 + dir*256 + c8*8) = vv;
            }
        }
        // write staged xg to LDS
        #pragma unroll
        for (int i=0;i<6;++i){
            int v = i*256 + tid;
            int row = v / 96, c8 = v - row*96;
            *(f16x8*)(&xg_lds[row][c8*8]) = stg[i];
        }
        __syncthreads();
        // compute steps (no global memory inside)
        for (int j = 0; j < jmax; ++j){
            f32x4 acc[12] = {};
            #pragma unroll
            for (int kk=0; kk<8; ++kk){
                bf16x8 a = *(const bf16x8*)(&h_lds[r16][kk*32 + kq*8]);
                #pragma unroll
                for (int tt=0; tt<12; ++tt)
                    acc[tt] = __builtin_amdgcn_mfma_f32_16x16x32_bf16(a, wf[tt][kk], acc[tt], 0,0,0);
            }
            if (lane < 16){
                #pragma unroll
                for (int c=0;c<4;++c){
                    int g = 64*w + 16*c + r16;
                    float hr = acc[c][0]   + bhr[c];
                    float hz = acc[4+c][0] + bhz[c];
                    float hn = acc[8+c][0] + bhn[c];
                    float xr = (float)xg_lds[j][g];
                    float xz = (float)xg_lds[j][256+g];
                    float xn = (float)xg_lds[j][512+g];
                    float rr = sigm(xr + hr);
                    float z2 = sigm(xz + hz);
                    float nc = tanh_fast(xn + rr*hn);
                    hreg[c] = (1.0f - z2)*nc + z2*hreg[c];
                    go_lds[j][g] = (f16_t)hreg[c];
                    h_lds[0][g]  = (bf16_t)hreg[c];
                }
            }
            __syncthreads();
        }
    }
    // final flush (last chunk: jlast valid rows)
    {
        const int pbase = t0 + (nch-1)*CH;
        const int jlast = t_end - pbase;
        #pragma unroll
        for (int q=0;q<2;++q){
            int v = q*256 + tid;
            int row = v >> 5, c8 = v & 31;
            if (row < jlast){
                int t = pbase + row;
                int pos = dir ? (NS-1-t) : t;
                f16x8 vv = *(const f16x8*)(&go_lds[row][c8*8]);
                *(f16x8*)(gout + ((size_t)b*NS + pos)*512 + dir*256 + c8*8) = vv;
            }
        }
    }
    if (lane < 16){
        #pragma unroll
        for (int c=0;c<4;++c)
            hidden[(size_t)b*512 + dir*256 + 64*w + 16*c + r16] = hreg[c];
    }
}

// ---------------- LayerNorm (wave per row) ----------------
template<int PASS>
__global__ __launch_bounds__(256,4) void ln_k(
    const void* __restrict__ src1, const float* __restrict__ src2,
    const float* __restrict__ gg, const float* __restrict__ bb,
    void* __restrict__ dst)
{
    int row = blockIdx.x*4 + (threadIdx.x>>6);
    int lane = threadIdx.x & 63;
    int c0 = lane*8;
    float x[8];
    if (PASS==1){
        f16x8 v = *(const f16x8*)((const f16_t*)src1 + (size_t)row*512 + c0);
        #pragma unroll
        for (int i=0;i<8;++i) x[i] = (float)v[i];
    } else {
        bf16x8 v = *(const bf16x8*)((const bf16_t*)src1 + (size_t)row*512 + c0);
        const float* q = src2 + (size_t)row*512 + c0;
        float4 q0 = *(const float4*)q, q1 = *(const float4*)(q+4);
        x[0]=(float)v[0]+q0.x; x[1]=(float)v[1]+q0.y; x[2]=(float)v[2]+q0.z; x[3]=(float)v[3]+q0.w;
        x[4]=(float)v[4]+q1.x; x[5]=(float)v[5]+q1.y; x[6]=(float)v[6]+q1.z; x[7]=(float)v[7]+q1.w;
    }
    float s=0.f, sq=0.f;
    #pragma unroll
    for (int i=0;i<8;++i){ s += x[i]; sq += x[i]*x[i]; }
    #pragma unroll
    for (int m=1; m<64; m<<=1){ s += __shfl_xor(s, m, 64); sq += __shfl_xor(sq, m, 64); }
    float mu = s * (1.0f/512.0f);
    float var = sq * (1.0f/512.0f) - mu*mu;
    float rs = rsqrtf(var + 1e-5f);
    if (PASS==1){
        bf16x8 o;
        #pragma unroll
        for (int i=0;i<8;++i) o[i] = (bf16_t)((x[i]-mu)*rs*gg[c0+i] + bb[c0+i]);
        *(bf16x8*)((bf16_t*)dst + (size_t)row*512 + c0) = o;
    } else {
        float y[8];
        #pragma unroll
        for (int i=0;i<8;++i) y[i] = (x[i]-mu)*rs*gg[c0+i] + bb[c0+i];
        float* dp = (float*)dst + (size_t)row*512 + c0;
        *(float4*)dp     = make_float4(y[0],y[1],y[2],y[3]);
        *(float4*)(dp+4) = make_float4(y[4],y[5],y[6],y[7]);
    }
}

// ---------------- attention: block = (qblock64, head, batch) ----------------
__global__ __launch_bounds__(256,2) void attn_k(
    const bf16_t* __restrict__ qkv,      // [3][B][H][S][DK]
    const int* __restrict__ lengths,
    bf16_t* __restrict__ concat)         // (B*S, 512)
{
    const int qb = blockIdx.x, hh = blockIdx.y, b = blockIdx.z;
    const int tid = threadIdx.x, lane = tid & 63, w = tid >> 6;
    const int r16 = lane & 15, kq = lane >> 4;
    const int len = lengths[b];
    const size_t bh = ((size_t)b*NH + hh)*NS*DKq;
    const bf16_t* Q = qkv + bh;
    const bf16_t* K = qkv + (size_t)NB*NH*NS*DKq + bh;
    const bf16_t* V = qkv + 2*(size_t)NB*NH*NS*DKq + bh;

    __shared__ __align__(16) bf16_t VT[32][520];
    __shared__ __align__(16) bf16_t P[4][16][40];

    const int q0 = qb*64 + w*16;
    bf16x8 aq[2];
    #pragma unroll
    for (int kk=0; kk<2; ++kk)
        aq[kk] = *(const bf16x8*)(Q + (size_t)(q0+r16)*DKq + kk*32 + kq*8);

    f32x4 sc[32] = {};
    #pragma unroll
    for (int t=0;t<32;++t){
        #pragma unroll
        for (int kk=0;kk<2;++kk){
            bf16x8 bk = *(const bf16x8*)(K + (size_t)(t*16+r16)*DKq + kk*32 + kq*8);
            sc[t] = __builtin_amdgcn_mfma_f32_16x16x32_bf16(aq[kk], bk, sc[t], 0,0,0);
        }
    }
    float mx[4] = {-3e38f,-3e38f,-3e38f,-3e38f};
    #pragma unroll
    for (int t=0;t<32;++t){
        bool valid = (t*16 + r16) < len;
        #pragma unroll
        for (int r=0;r<4;++r){
            float sv = valid ? sc[t][r]*0.125f : -3e38f;
            sc[t][r] = sv;
            mx[r] = fmaxf(mx[r], sv);
        }
    }
    #pragma unroll
    for (int m=1;m<16;m<<=1)
        #pragma unroll
        for (int r=0;r<4;++r) mx[r] = fmaxf(mx[r], __shfl_xor(mx[r], m, 64));
    float sm[4] = {0.f,0.f,0.f,0.f};
    #pragma unroll
    for (int t=0;t<32;++t){
        bool valid = (t*16 + r16) < len;
        #pragma unroll
        for (int r=0;r<4;++r){
            float p = valid ? __expf(sc[t][r] - mx[r]) : 0.0f;
            sc[t][r] = p;
            sm[r] += p;
        }
    }
    #pragma unroll
    for (int m=1;m<16;m<<=1)
        #pragma unroll
        for (int r=0;r<4;++r) sm[r] += __shfl_xor(sm[r], m, 64);
    float rs[4];
    #pragma unroll
    for (int r=0;r<4;++r) rs[r] = sm[r] > 0.f ? 1.0f/sm[r] : 0.0f;

    f32x4 ao[4] = {};
    #pragma unroll
    for (int half=0; half<2; ++half){
        __syncthreads();
        #pragma unroll
        for (int rr=0; rr<2; ++rr){
            int s = tid*2 + rr;
            const bf16_t* vp = V + (size_t)s*DKq + half*32;
            bf16x8 v0 = *(const bf16x8*)(vp);
            bf16x8 v1 = *(const bf16x8*)(vp+8);
            bf16x8 v2 = *(const bf16x8*)(vp+16);
            bf16x8 v3 = *(const bf16x8*)(vp+24);
            #pragma unroll
            for (int d=0; d<8; ++d){
                VT[d][s]=v0[d]; VT[8+d][s]=v1[d]; VT[16+d][s]=v2[d]; VT[24+d][s]=v3[d];
            }
        }
        __syncthreads();
        #pragma unroll
        for (int c=0;c<16;++c){
            #pragma unroll
            for (int tt=0;tt<2;++tt)
                #pragma unroll
                for (int r=0;r<4;++r)
                    P[w][kq*4 + r][tt*16 + r16] = (bf16_t)(sc[2*c+tt][r] * rs[r]);
            bf16x8 pa = *(const bf16x8*)(&P[w][r16][kq*8]);
            #pragma unroll
            for (int jt=0;jt<2;++jt){
                bf16x8 bvv = *(const bf16x8*)(&VT[jt*16 + r16][c*32 + kq*8]);
                ao[half*2+jt] = __builtin_amdgcn_mfma_f32_16x16x32_bf16(pa, bvv, ao[half*2+jt], 0,0,0);
            }
        }
    }
    #pragma unroll
    for (int ht=0; ht<4; ++ht){
        int d = (ht>>1)*32 + ((ht&1)*16) + r16;
        #pragma unroll
        for (int r=0;r<4;++r){
            int s = q0 + kq*4 + r;
            float v = (s < len) ? ao[ht][r] : 0.0f;
            concat[((size_t)b*NS + s)*512 + hh*DKq + d] = (bf16_t)v;
        }
    }
}

// ---------------- launch ----------------
extern "C" void kernel_launch(void* const* d_in, const int* in_sizes, int n_in,
                              void* d_out, int out_size, void* d_ws, size_t ws_size,
                              hipStream_t stream){
    (void)in_sizes; (void)n_in; (void)out_size; (void)ws_size;
    const float* splits = (const float*)d_in[0];
    const float* w_ih_f = (const float*)d_in[1];
    const float* w_hh_f = (const float*)d_in[2];
    const float* b_ih_f = (const float*)d_in[3];
    const float* b_hh_f = (const float*)d_in[4];
    const float* w_ih_b = (const float*)d_in[5];
    const float* w_hh_b = (const float*)d_in[6];
    const float* b_ih_b = (const float*)d_in[7];
    const float* b_hh_b = (const float*)d_in[8];
    const float* ln1_g  = (const float*)d_in[9];
    const float* ln1_b  = (const float*)d_in[10];
    const float* wq     = (const float*)d_in[11];
    const float* bq     = (const float*)d_in[12];
    const float* wk     = (const float*)d_in[13];
    const float* bk_    = (const float*)d_in[14];
    const float* wv     = (const float*)d_in[15];
    const float* bv     = (const float*)d_in[16];
    const float* wo     = (const float*)d_in[17];
    const float* bo     = (const float*)d_in[18];
    const float* ln2_g  = (const float*)d_in[19];
    const float* ln2_b  = (const float*)d_in[20];
    const int* lengths  = (const int*)d_in[21];
    const int* masks    = (const int*)d_in[22];

    char* ws = (char*)d_ws;
    bf16_t* splits16 = (bf16_t*)(ws);                       // 16MB ; later: concat
    f16_t*  xgbuf    = (f16_t*)(ws + ((size_t)16<<20));     // 48MB ; later: qkv / obuf
    f16_t*  gout     = (f16_t*)(ws + ((size_t)64<<20));     // 16MB
    bf16_t* ln1out   = (bf16_t*)(ws + ((size_t)80<<20));    // 16MB
    bf16_t* wih16    = (bf16_t*)(ws + ((size_t)96<<20));    // 1.5MB
    bf16_t* wqkv16   = (bf16_t*)(ws + ((size_t)98<<20));    // 1.5MB
    bf16_t* wo16     = (bf16_t*)(ws + ((size_t)100<<20));   // 0.5MB
    float*  bih      = (float*)(ws + ((size_t)101<<20));    // 6KB
    float*  bqkv     = (float*)(ws + ((size_t)101<<20) + 8192);
    bf16_t* qkv      = (bf16_t*)xgbuf;                      // overlay (after scan consumes xg)
    float*  obuf     = (float*)xgbuf;                       // overlay (after attn consumes qkv)
    bf16_t* concat   = (bf16_t*)splits16;                   // overlay (after xg gemm)

    float* out_f = (float*)d_out;
    float* hid   = out_f + (size_t)NB*NS*ND;

    // ---- converts / copies ----
    hipLaunchKernelGGL(cvt_f32_bf16_k, dim3(8192), dim3(256), 0, stream, splits, splits16, 2097152);
    hipLaunchKernelGGL(cvt_f32_bf16_k, dim3(384),  dim3(256), 0, stream, w_ih_f, wih16,          98304);
    hipLaunchKernelGGL(cvt_f32_bf16_k, dim3(384),  dim3(256), 0, stream, w_ih_b, wih16+393216,   98304);
    hipLaunchKernelGGL(cvt_f32_bf16_k, dim3(256),  dim3(256), 0, stream, wq, wqkv16,             65536);
    hipLaunchKernelGGL(cvt_f32_bf16_k, dim3(256),  dim3(256), 0, stream, wk, wqkv16+262144,      65536);
    hipLaunchKernelGGL(cvt_f32_bf16_k, dim3(256),  dim3(256), 0, stream, wv, wqkv16+524288,      65536);
    hipLaunchKernelGGL(cvt_f32_bf16_k, dim3(256),  dim3(256), 0, stream, wo, wo16,               65536);
    hipMemcpyAsync(bih,       b_ih_f, 768*4, hipMemcpyDeviceToDevice, stream);
    hipMemcpyAsync(bih+768,   b_ih_b, 768*4, hipMemcpyDeviceToDevice, stream);
    hipMemcpyAsync(bqkv,      bq,     512*4, hipMemcpyDeviceToDevice, stream);
    hipMemcpyAsync(bqkv+512,  bk_,    512*4, hipMemcpyDeviceToDevice, stream);
    hipMemcpyAsync(bqkv+1024, bv,     512*4, hipMemcpyDeviceToDevice, stream);
    hipMemsetAsync(gout, 0, (size_t)16<<20, stream);

    // ---- xg = splits @ w_ih^T + b_ih ----
    hipLaunchKernelGGL((gemm_k<0>), dim3(12,128), dim3(256), 0, stream,
                       splits16, wih16, bih, (void*)xgbuf, nullptr, 1536);
    // ---- GRU scan ----
    hipLaunchKernelGGL(gru_scan_k, dim3(64), dim3(256), 0, stream,
                       xgbuf, w_hh_f, w_hh_b, b_hh_f, b_hh_b, lengths, gout, hid);
    // ---- LN1 ----
    hipLaunchKernelGGL((ln_k<1>), dim3(4096), dim3(256), 0, stream,
                       (const void*)gout, nullptr, ln1_g, ln1_b, (void*)ln1out);
    // ---- qkv ----
    hipLaunchKernelGGL((gemm_k<1>), dim3(12,128), dim3(256), 0, stream,
                       ln1out, wqkv16, bqkv, (void*)qkv, nullptr, 0);
    // ---- attention ----
    hipLaunchKernelGGL(attn_k, dim3(8,8,32), dim3(256), 0, stream, qkv, lengths, concat);
    // ---- o = concat @ wo^T + bo, row-masked ----
    hipLaunchKernelGGL((gemm_k<2>), dim3(4,128), dim3(256), 0, stream,
                       concat, wo16, bo, (void*)obuf, masks, 512);
    // ---- LN2 -> d_out ----
    hipLaunchKernelGGL((ln_k<2>), dim3(4096), dim3(256), 0, stream,
                       (const void*)ln1out, obuf, ln2_g, ln2_b, (void*)out_f);
}

// Round 5
// 1178.061 us; speedup vs baseline: 1.2811x; 1.2811x over previous
//
#include <hip/hip_runtime.h>
#include <hip/hip_bf16.h>
#include <hip/hip_fp16.h>

// Context encoder: BiGRU(256) -> LN1 -> MHA(8x64, masked) -> +res LN2
// Round 5: round-4 structure + h_row DOUBLE BUFFER in the scan.
// Race fixed: step j reads h_row[hp], writes h_row[hp^1]; per-step barrier
// orders both directions. (Round 4's single h_row had an intra-barrier
// RAW/WAR race between one wave's late A-fragment ds_read and another
// wave's gate-phase write at 2 waves/SIMD.)

typedef __bf16 bf16_t;
typedef _Float16 f16_t;
typedef __bf16 bf16x8 __attribute__((ext_vector_type(8)));
typedef __bf16 bf16x4 __attribute__((ext_vector_type(4)));
typedef _Float16 f16x8 __attribute__((ext_vector_type(8)));
typedef float f32x4 __attribute__((ext_vector_type(4)));

#define NB 32
#define NS 512
#define ND 512
#define NH 8
#define DKq 64
#define CH 16

static __device__ __forceinline__ float sigm(float x){ return 1.0f/(1.0f+__expf(-x)); }
static __device__ __forceinline__ float tanh_fast(float x){ return 1.0f - 2.0f/(__expf(2.0f*x)+1.0f); }

// ---------------- fp32 -> bf16 convert ----------------
__global__ void cvt_f32_bf16_k(const float* __restrict__ src, bf16_t* __restrict__ dst, int n4){
    int i = blockIdx.x*256 + threadIdx.x;
    if (i < n4){
        float4 v = ((const float4*)src)[i];
        bf16x4 o; o[0]=(bf16_t)v.x; o[1]=(bf16_t)v.y; o[2]=(bf16_t)v.z; o[3]=(bf16_t)v.w;
        ((bf16x4*)dst)[i] = o;
    }
}

// ---------------- generic bf16 MFMA GEMM: C = A(M,512) @ W(N,512)^T + bias ----------------
// MODE 0: f16 out split: col<768 -> out (xg_f), col>=768 -> out2 (xg_b), ld 768.
// MODE 1: scatter bf16 to qkv[3][B][H][S][DK].  MODE 2: fp32 out, ldc=N, row-masked.
template<int MODE>
__global__ __launch_bounds__(256,2) void gemm_k(
    const bf16_t* __restrict__ A, const bf16_t* __restrict__ W,
    const float* __restrict__ bias, void* __restrict__ out, void* __restrict__ out2,
    const int* __restrict__ masks, int N)
{
    const int lane = threadIdx.x & 63;
    const int wv = threadIdx.x >> 6;
    const int wr = wv >> 1, wc = wv & 1;
    const int m0 = blockIdx.y*128 + wr*64;
    const int n0 = blockIdx.x*128 + wc*64;
    const int r16 = lane & 15, kq = lane >> 4;
    f32x4 acc[4][4] = {};
    const bf16_t* Ap = A + (size_t)(m0 + r16)*512 + kq*8;
    const bf16_t* Wp = W + (size_t)(n0 + r16)*512 + kq*8;
    #pragma unroll
    for (int kk = 0; kk < 16; ++kk){
        bf16x8 a[4], b[4];
        #pragma unroll
        for (int i=0;i<4;++i) a[i] = *(const bf16x8*)(Ap + (size_t)i*16*512 + kk*32);
        #pragma unroll
        for (int j=0;j<4;++j) b[j] = *(const bf16x8*)(Wp + (size_t)j*16*512 + kk*32);
        #pragma unroll
        for (int i=0;i<4;++i)
            #pragma unroll
            for (int j=0;j<4;++j)
                acc[i][j] = __builtin_amdgcn_mfma_f32_16x16x32_bf16(a[i], b[j], acc[i][j], 0,0,0);
    }
    #pragma unroll
    for (int i=0;i<4;++i){
        int row_base = m0 + i*16 + kq*4;
        #pragma unroll
        for (int j=0;j<4;++j){
            int col = n0 + j*16 + r16;
            float bs = bias[col];
            #pragma unroll
            for (int r=0;r<4;++r){
                int row = row_base + r;
                float v = acc[i][j][r] + bs;
                if (MODE==0){
                    if (col < 768) ((f16_t*)out)[(size_t)row*768 + col] = (f16_t)v;
                    else           ((f16_t*)out2)[(size_t)row*768 + (col-768)] = (f16_t)v;
                } else if (MODE==1){
                    int which = col >> 9, hh = (col >> 6) & 7, d = col & 63;
                    int bb = row >> 9, s = row & 511;
                    ((bf16_t*)out)[((((size_t)which*NB + bb)*NH + hh)*NS + s)*DKq + d] = (bf16_t)v;
                } else {
                    float mrow = (float)masks[row];
                    ((float*)out)[(size_t)row*N + col] = v * mrow;
                }
            }
        }
    }
}

// ---------------- GRU scan: one block per (batch, dir), 8 waves ----------------
// Wave w owns h-slice [32w, 32w+32): tile tt (g=tt>>1, u=tt&1) -> n0 = g*256 + 32w + 16u.
// After MFMA, lane r16 (kq==0), reg 0 of acc[g*2+u] = hg[g][32w+16u+r16].
__global__ __launch_bounds__(512,2) void gru_scan_k(
    const f16_t* __restrict__ xg_f, const f16_t* __restrict__ xg_b,   // (B*S, 768) each
    const float* __restrict__ whh_f, const float* __restrict__ whh_b,
    const float* __restrict__ bhh_f, const float* __restrict__ bhh_b,
    const int* __restrict__ lengths,
    f16_t* __restrict__ gout,              // (B*S, 512) pre-zeroed
    float* __restrict__ hidden)            // (B, 512)
{
    const int b = blockIdx.x >> 1, dir = blockIdx.x & 1;
    const int tid = threadIdx.x, lane = tid & 63, w = tid >> 6;
    const int r16 = lane & 15, kq = lane >> 4;
    const float* whh = dir ? whh_b : whh_f;
    const float* bhh = dir ? bhh_b : bhh_f;
    const f16_t* xgd = dir ? xg_b : xg_f;
    const int len = lengths[b];

    __shared__ __align__(16) f16_t  xg_lds[2][CH][768];   // 48KB double buffer
    __shared__ __align__(16) f16_t  go_lds[CH][256];      // 8KB output buffer
    __shared__ __align__(16) bf16_t h_row[2][256];        // 1KB h state, double-buffered

    ((bf16_t*)h_row)[tid] = (bf16_t)0.0f;                 // 512 threads cover both buffers

    const int t0 = dir ? (NS - len) : 0;
    const int t_end = dir ? NS : len;
    const int nch = (len + CH - 1) / CH;

    auto issue_chunk = [&](int ci, int buf){
        int base = t0 + ci*CH;
        int jmax = min(CH, t_end - base);
        int pstart = dir ? (NS - base - jmax) : base;
        const char* gp = (const char*)(xgd + ((size_t)b*NS + pstart)*768);
        char* lp = (char*)(&xg_lds[buf][0][0]);
        int bytes = jmax*1536;
        #pragma unroll
        for (int k2=0; k2<3; ++k2){
            int off = (w*3 + k2)*1024;
            if (off < bytes){
                __builtin_amdgcn_global_load_lds(
                    (const __attribute__((address_space(1))) void*)(gp + off + (size_t)lane*16),
                    (__attribute__((address_space(3))) void*)(lp + off), 16, 0, 0);
            }
        }
    };
    issue_chunk(0, 0);

    // weight fragments: 6 tiles x 8 k-chunks = 192 VGPRs
    bf16x8 wf[6][8];
    #pragma unroll
    for (int tt=0; tt<6; ++tt){
        int g = tt >> 1, u = tt & 1;
        int n0 = g*256 + 32*w + u*16;
        const float* wp = whh + (size_t)(n0 + r16)*256 + kq*8;
        #pragma unroll
        for (int kk=0; kk<8; ++kk){
            float4 v0 = *(const float4*)(wp + kk*32);
            float4 v1 = *(const float4*)(wp + kk*32 + 4);
            bf16x8 f;
            f[0]=(bf16_t)v0.x; f[1]=(bf16_t)v0.y; f[2]=(bf16_t)v0.z; f[3]=(bf16_t)v0.w;
            f[4]=(bf16_t)v1.x; f[5]=(bf16_t)v1.y; f[6]=(bf16_t)v1.z; f[7]=(bf16_t)v1.w;
            wf[tt][kk] = f;
        }
    }
    float bhr[2], bhz[2], bhn[2], hreg[2];
    #pragma unroll
    for (int u=0; u<2; ++u){
        int gi = 32*w + 16*u + r16;
        bhr[u] = bhh[gi]; bhz[u] = bhh[256+gi]; bhn[u] = bhh[512+gi];
        hreg[u] = 0.0f;
    }

    int hp = 0;   // h parity: read h_row[hp], write h_row[hp^1]
    for (int ci = 0; ci < nch; ++ci){
        const int cur = ci & 1;
        const int base = t0 + ci*CH;
        const int jmax = min(CH, t_end - base);
        __syncthreads();                      // buf[cur] loads complete + all waves synced
        if (ci + 1 < nch) issue_chunk(ci+1, cur^1);
        for (int j = 0; j < jmax; ++j){
            const int xrow = dir ? (jmax-1-j) : j;
            f32x4 acc[6] = {};
            #pragma unroll
            for (int kk=0; kk<8; ++kk){
                bf16x8 a = {};
                if (r16 == 0) a = *(const bf16x8*)(&h_row[hp][kk*32 + kq*8]);
                #pragma unroll
                for (int tt=0; tt<6; ++tt)
                    acc[tt] = __builtin_amdgcn_mfma_f32_16x16x32_bf16(a, wf[tt][kk], acc[tt], 0,0,0);
            }
            if (lane < 16){
                #pragma unroll
                for (int u=0; u<2; ++u){
                    int gi = 32*w + 16*u + r16;
                    float hr = acc[u][0]   + bhr[u];
                    float hz = acc[2+u][0] + bhz[u];
                    float hn = acc[4+u][0] + bhn[u];
                    float xr = (float)xg_lds[cur][xrow][gi];
                    float xz = (float)xg_lds[cur][xrow][256+gi];
                    float xn = (float)xg_lds[cur][xrow][512+gi];
                    float rr = sigm(xr + hr);
                    float z2 = sigm(xz + hz);
                    float nc = tanh_fast(xn + rr*hn);
                    hreg[u] = (1.0f - z2)*nc + z2*hreg[u];
                    go_lds[j][gi]    = (f16_t)hreg[u];
                    h_row[hp^1][gi]  = (bf16_t)hreg[u];
                }
            }
            hp ^= 1;
            __syncthreads();
        }
        // flush chunk ci (rows < jmax); next iteration's barrier orders reuse
        {
            int row = tid >> 5, c8 = tid & 31;
            if (row < jmax){
                int t = base + row;
                int pos = dir ? (NS-1-t) : t;
                f16x8 vv = *(const f16x8*)(&go_lds[row][c8*8]);
                *(f16x8*)(gout + ((size_t)b*NS + pos)*512 + dir*256 + c8*8) = vv;
            }
        }
    }
    if (lane < 16){
        #pragma unroll
        for (int u=0; u<2; ++u)
            hidden[(size_t)b*512 + dir*256 + 32*w + 16*u + r16] = hreg[u];
    }
}

// ---------------- LayerNorm (wave per row) ----------------
template<int PASS>
__global__ __launch_bounds__(256,4) void ln_k(
    const void* __restrict__ src1, const float* __restrict__ src2,
    const float* __restrict__ gg, const float* __restrict__ bb,
    void* __restrict__ dst)
{
    int row = blockIdx.x*4 + (threadIdx.x>>6);
    int lane = threadIdx.x & 63;
    int c0 = lane*8;
    float x[8];
    if (PASS==1){
        f16x8 v = *(const f16x8*)((const f16_t*)src1 + (size_t)row*512 + c0);
        #pragma unroll
        for (int i=0;i<8;++i) x[i] = (float)v[i];
    } else {
        bf16x8 v = *(const bf16x8*)((const bf16_t*)src1 + (size_t)row*512 + c0);
        const float* q = src2 + (size_t)row*512 + c0;
        float4 q0 = *(const float4*)q, q1 = *(const float4*)(q+4);
        x[0]=(float)v[0]+q0.x; x[1]=(float)v[1]+q0.y; x[2]=(float)v[2]+q0.z; x[3]=(float)v[3]+q0.w;
        x[4]=(float)v[4]+q1.x; x[5]=(float)v[5]+q1.y; x[6]=(float)v[6]+q1.z; x[7]=(float)v[7]+q1.w;
    }
    float s=0.f, sq=0.f;
    #pragma unroll
    for (int i=0;i<8;++i){ s += x[i]; sq += x[i]*x[i]; }
    #pragma unroll
    for (int m=1; m<64; m<<=1){ s += __shfl_xor(s, m, 64); sq += __shfl_xor(sq, m, 64); }
    float mu = s * (1.0f/512.0f);
    float var = sq * (1.0f/512.0f) - mu*mu;
    float rs = rsqrtf(var + 1e-5f);
    if (PASS==1){
        bf16x8 o;
        #pragma unroll
        for (int i=0;i<8;++i) o[i] = (bf16_t)((x[i]-mu)*rs*gg[c0+i] + bb[c0+i]);
        *(bf16x8*)((bf16_t*)dst + (size_t)row*512 + c0) = o;
    } else {
        float y[8];
        #pragma unroll
        for (int i=0;i<8;++i) y[i] = (x[i]-mu)*rs*gg[c0+i] + bb[c0+i];
        float* dp = (float*)dst + (size_t)row*512 + c0;
        *(float4*)dp     = make_float4(y[0],y[1],y[2],y[3]);
        *(float4*)(dp+4) = make_float4(y[4],y[5],y[6],y[7]);
    }
}

// ---------------- attention: block = (qblock64, head, batch) ----------------
__global__ __launch_bounds__(256,2) void attn_k(
    const bf16_t* __restrict__ qkv,      // [3][B][H][S][DK]
    const int* __restrict__ lengths,
    bf16_t* __restrict__ concat)         // (B*S, 512)
{
    const int qb = blockIdx.x, hh = blockIdx.y, b = blockIdx.z;
    const int tid = threadIdx.x, lane = tid & 63, w = tid >> 6;
    const int r16 = lane & 15, kq = lane >> 4;
    const int len = lengths[b];
    const size_t bh = ((size_t)b*NH + hh)*NS*DKq;
    const bf16_t* Q = qkv + bh;
    const bf16_t* K = qkv + (size_t)NB*NH*NS*DKq + bh;
    const bf16_t* V = qkv + 2*(size_t)NB*NH*NS*DKq + bh;

    __shared__ __align__(16) bf16_t VT[32][520];
    __shared__ __align__(16) bf16_t P[4][16][40];

    const int q0 = qb*64 + w*16;
    bf16x8 aq[2];
    #pragma unroll
    for (int kk=0; kk<2; ++kk)
        aq[kk] = *(const bf16x8*)(Q + (size_t)(q0+r16)*DKq + kk*32 + kq*8);

    f32x4 sc[32] = {};
    #pragma unroll
    for (int t=0;t<32;++t){
        #pragma unroll
        for (int kk=0;kk<2;++kk){
            bf16x8 bk = *(const bf16x8*)(K + (size_t)(t*16+r16)*DKq + kk*32 + kq*8);
            sc[t] = __builtin_amdgcn_mfma_f32_16x16x32_bf16(aq[kk], bk, sc[t], 0,0,0);
        }
    }
    float mx[4] = {-3e38f,-3e38f,-3e38f,-3e38f};
    #pragma unroll
    for (int t=0;t<32;++t){
        bool valid = (t*16 + r16) < len;
        #pragma unroll
        for (int r=0;r<4;++r){
            float sv = valid ? sc[t][r]*0.125f : -3e38f;
            sc[t][r] = sv;
            mx[r] = fmaxf(mx[r], sv);
        }
    }
    #pragma unroll
    for (int m=1;m<16;m<<=1)
        #pragma unroll
        for (int r=0;r<4;++r) mx[r] = fmaxf(mx[r], __shfl_xor(mx[r], m, 64));
    float sm[4] = {0.f,0.f,0.f,0.f};
    #pragma unroll
    for (int t=0;t<32;++t){
        bool valid = (t*16 + r16) < len;
        #pragma unroll
        for (int r=0;r<4;++r){
            float p = valid ? __expf(sc[t][r] - mx[r]) : 0.0f;
            sc[t][r] = p;
            sm[r] += p;
        }
    }
    #pragma unroll
    for (int m=1;m<16;m<<=1)
        #pragma unroll
        for (int r=0;r<4;++r) sm[r] += __shfl_xor(sm[r], m, 64);
    float rs[4];
    #pragma unroll
    for (int r=0;r<4;++r) rs[r] = sm[r] > 0.f ? 1.0f/sm[r] : 0.0f;

    f32x4 ao[4] = {};
    #pragma unroll
    for (int half=0; half<2; ++half){
        __syncthreads();
        #pragma unroll
        for (int rr=0; rr<2; ++rr){
            int s = tid*2 + rr;
            const bf16_t* vp = V + (size_t)s*DKq + half*32;
            bf16x8 v0 = *(const bf16x8*)(vp);
            bf16x8 v1 = *(const bf16x8*)(vp+8);
            bf16x8 v2 = *(const bf16x8*)(vp+16);
            bf16x8 v3 = *(const bf16x8*)(vp+24);
            #pragma unroll
            for (int d=0; d<8; ++d){
                VT[d][s]=v0[d]; VT[8+d][s]=v1[d]; VT[16+d][s]=v2[d]; VT[24+d][s]=v3[d];
            }
        }
        __syncthreads();
        #pragma unroll
        for (int c=0;c<16;++c){
            #pragma unroll
            for (int tt=0;tt<2;++tt)
                #pragma unroll
                for (int r=0;r<4;++r)
                    P[w][kq*4 + r][tt*16 + r16] = (bf16_t)(sc[2*c+tt][r] * rs[r]);
            bf16x8 pa = *(const bf16x8*)(&P[w][r16][kq*8]);
            #pragma unroll
            for (int jt=0;jt<2;++jt){
                bf16x8 bvv = *(const bf16x8*)(&VT[jt*16 + r16][c*32 + kq*8]);
                ao[half*2+jt] = __builtin_amdgcn_mfma_f32_16x16x32_bf16(pa, bvv, ao[half*2+jt], 0,0,0);
            }
        }
    }
    #pragma unroll
    for (int ht=0; ht<4; ++ht){
        int d = (ht>>1)*32 + ((ht&1)*16) + r16;
        #pragma unroll
        for (int r=0;r<4;++r){
            int s = q0 + kq*4 + r;
            float v = (s < len) ? ao[ht][r] : 0.0f;
            concat[((size_t)b*NS + s)*512 + hh*DKq + d] = (bf16_t)v;
        }
    }
}

// ---------------- launch ----------------
extern "C" void kernel_launch(void* const* d_in, const int* in_sizes, int n_in,
                              void* d_out, int out_size, void* d_ws, size_t ws_size,
                              hipStream_t stream){
    (void)in_sizes; (void)n_in; (void)out_size; (void)ws_size;
    const float* splits = (const float*)d_in[0];
    const float* w_ih_f = (const float*)d_in[1];
    const float* w_hh_f = (const float*)d_in[2];
    const float* b_ih_f = (const float*)d_in[3];
    const float* b_hh_f = (const float*)d_in[4];
    const float* w_ih_b = (const float*)d_in[5];
    const float* w_hh_b = (const float*)d_in[6];
    const float* b_ih_b = (const float*)d_in[7];
    const float* b_hh_b = (const float*)d_in[8];
    const float* ln1_g  = (const float*)d_in[9];
    const float* ln1_b  = (const float*)d_in[10];
    const float* wq     = (const float*)d_in[11];
    const float* bq     = (const float*)d_in[12];
    const float* wk     = (const float*)d_in[13];
    const float* bk_    = (const float*)d_in[14];
    const float* wv     = (const float*)d_in[15];
    const float* bv     = (const float*)d_in[16];
    const float* wo     = (const float*)d_in[17];
    const float* bo     = (const float*)d_in[18];
    const float* ln2_g  = (const float*)d_in[19];
    const float* ln2_b  = (const float*)d_in[20];
    const int* lengths  = (const int*)d_in[21];
    const int* masks    = (const int*)d_in[22];

    char* ws = (char*)d_ws;
    bf16_t* splits16 = (bf16_t*)(ws);                       // 16MB ; later: concat
    f16_t*  xg_f     = (f16_t*)(ws + ((size_t)16<<20));     // 24MB
    f16_t*  xg_b     = (f16_t*)(ws + ((size_t)40<<20));     // 24MB
    f16_t*  gout     = (f16_t*)(ws + ((size_t)64<<20));     // 16MB
    bf16_t* ln1out   = (bf16_t*)(ws + ((size_t)80<<20));    // 16MB
    bf16_t* wih16    = (bf16_t*)(ws + ((size_t)96<<20));    // 1.5MB
    bf16_t* wqkv16   = (bf16_t*)(ws + ((size_t)98<<20));    // 1.5MB
    bf16_t* wo16     = (bf16_t*)(ws + ((size_t)100<<20));   // 0.5MB
    float*  bih      = (float*)(ws + ((size_t)101<<20));    // 6KB
    float*  bqkv     = (float*)(ws + ((size_t)101<<20) + 8192);
    bf16_t* qkv      = (bf16_t*)xg_f;                       // overlay 16..64MB (after scan)
    float*  obuf     = (float*)xg_f;                        // overlay (after attn)
    bf16_t* concat   = (bf16_t*)splits16;                   // overlay (after xg gemm)

    float* out_f = (float*)d_out;
    float* hid   = out_f + (size_t)NB*NS*ND;

    // ---- converts / copies ----
    hipLaunchKernelGGL(cvt_f32_bf16_k, dim3(8192), dim3(256), 0, stream, splits, splits16, 2097152);
    hipLaunchKernelGGL(cvt_f32_bf16_k, dim3(384),  dim3(256), 0, stream, w_ih_f, wih16,          98304);
    hipLaunchKernelGGL(cvt_f32_bf16_k, dim3(384),  dim3(256), 0, stream, w_ih_b, wih16+393216,   98304);
    hipLaunchKernelGGL(cvt_f32_bf16_k, dim3(256),  dim3(256), 0, stream, wq, wqkv16,             65536);
    hipLaunchKernelGGL(cvt_f32_bf16_k, dim3(256),  dim3(256), 0, stream, wk, wqkv16+262144,      65536);
    hipLaunchKernelGGL(cvt_f32_bf16_k, dim3(256),  dim3(256), 0, stream, wv, wqkv16+524288,      65536);
    hipLaunchKernelGGL(cvt_f32_bf16_k, dim3(256),  dim3(256), 0, stream, wo, wo16,               65536);
    hipMemcpyAsync(bih,       b_ih_f, 768*4, hipMemcpyDeviceToDevice, stream);
    hipMemcpyAsync(bih+768,   b_ih_b, 768*4, hipMemcpyDeviceToDevice, stream);
    hipMemcpyAsync(bqkv,      bq,     512*4, hipMemcpyDeviceToDevice, stream);
    hipMemcpyAsync(bqkv+512,  bk_,    512*4, hipMemcpyDeviceToDevice, stream);
    hipMemcpyAsync(bqkv+1024, bv,     512*4, hipMemcpyDeviceToDevice, stream);
    hipMemsetAsync(gout, 0, (size_t)16<<20, stream);

    // ---- xg = splits @ w_ih^T + b_ih (split fwd/bwd outputs) ----
    hipLaunchKernelGGL((gemm_k<0>), dim3(12,128), dim3(256), 0, stream,
                       splits16, wih16, bih, (void*)xg_f, (void*)xg_b, nullptr, 1536);
    // ---- GRU scan ----
    hipLaunchKernelGGL(gru_scan_k, dim3(64), dim3(512), 0, stream,
                       xg_f, xg_b, w_hh_f, w_hh_b, b_hh_f, b_hh_b, lengths, gout, hid);
    // ---- LN1 ----
    hipLaunchKernelGGL((ln_k<1>), dim3(4096), dim3(256), 0, stream,
                       (const void*)gout, nullptr, ln1_g, ln1_b, (void*)ln1out);
    // ---- qkv ----
    hipLaunchKernelGGL((gemm_k<1>), dim3(12,128), dim3(256), 0, stream,
                       ln1out, wqkv16, bqkv, (void*)qkv, nullptr, nullptr, 0);
    // ---- attention ----
    hipLaunchKernelGGL(attn_k, dim3(8,8,32), dim3(256), 0, stream, qkv, lengths, concat);
    // ---- o = concat @ wo^T + bo, row-masked ----
    hipLaunchKernelGGL((gemm_k<2>), dim3(4,128), dim3(256), 0, stream,
                       concat, wo16, bo, (void*)obuf, nullptr, masks, 512);
    // ---- LN2 -> d_out ----
    hipLaunchKernelGGL((ln_k<2>), dim3(4096), dim3(256), 0, stream,
                       (const void*)ln1out, obuf, ln2_g, ln2_b, (void*)out_f);
}